// Round 12
// baseline (195.989 us; speedup 1.0000x reference)
//
#include <hip/hip_runtime.h>
#include <hip/hip_bf16.h>
#include <math.h>

#define NB 8192
#define ND 1024
#define KEPS 1e-8f
#define SLOTS 128
#define NTIL 64           // 8192/128 tile grid
#define NWG 2080          // NTIL*(NTIL+1)/2 (= 8*260, XCD-bijective)
#define NKT 32            // K-tiles of 32

typedef __attribute__((ext_vector_type(8))) __bf16 bf16x8;
typedef __attribute__((ext_vector_type(4))) float f32x4;

// ---------- helpers ----------
__device__ __forceinline__ unsigned int fmono(float f) {
    unsigned int b = __float_as_uint(f);
    return b ^ ((b & 0x80000000u) ? 0xFFFFFFFFu : 0x80000000u);
}
__device__ __forceinline__ float fmono_inv(unsigned int m) {
    unsigned int b = (m & 0x80000000u) ? (m ^ 0x80000000u) : ~m;
    return __uint_as_float(b);
}
__device__ __forceinline__ unsigned short f2bf(float f) {
    union { float f; unsigned int u; } a;
    a.f = f;
    unsigned int lsb = (a.u >> 16) & 1u;
    a.u += 0x7fffu + lsb;
    return (unsigned short)(a.u >> 16);
}
__device__ __forceinline__ void gload_lds16(const void* g, void* l) {
    __builtin_amdgcn_global_load_lds(
        (const __attribute__((address_space(1))) unsigned int*)g,
        (__attribute__((address_space(3))) unsigned int*)l, 16, 0, 0);
}
__device__ __forceinline__ unsigned long long packmax(float mx, int mc) {
    return ((unsigned long long)fmono(mx) << 32) |
           (unsigned long long)(~(unsigned int)mc);
}

// ---------- kernel 1: row L2-normalize -> bf16; emit per-row {S=sum(xn), n2=||xn||^2} ----------
__global__ __launch_bounds__(256) void normalize_k(const float* __restrict__ x,
                                                   unsigned short* __restrict__ xnb,
                                                   float2* __restrict__ sn,
                                                   float* __restrict__ out) {
    if (blockIdx.x == 0 && threadIdx.x == 0) out[0] = 0.0f;  // atomic accumulator init
    int row = blockIdx.x * 4 + (threadIdx.x >> 6);
    int l = threadIdx.x & 63;
    const float4* xr = (const float4*)(x + (size_t)row * ND);
    float4 v[4];
    float ss = 0.f, sv = 0.f;
#pragma unroll
    for (int q = 0; q < 4; ++q) {
        v[q] = xr[q * 64 + l];
        ss += v[q].x * v[q].x + v[q].y * v[q].y + v[q].z * v[q].z + v[q].w * v[q].w;
        sv += v[q].x + v[q].y + v[q].z + v[q].w;
    }
#pragma unroll
    for (int off = 1; off < 64; off <<= 1) {
        ss += __shfl_xor(ss, off, 64);
        sv += __shfl_xor(sv, off, 64);
    }
    float scale = 1.0f / fmaxf(sqrtf(ss), KEPS);
    if (l == 0) sn[row] = make_float2(sv * scale, ss * scale * scale);
    ushort4* o = (ushort4*)(xnb + (size_t)row * ND);
#pragma unroll
    for (int q = 0; q < 4; ++q) {
        ushort4 u;
        u.x = f2bf(v[q].x * scale);
        u.y = f2bf(v[q].y * scale);
        u.z = f2bf(v[q].z * scale);
        u.w = f2bf(v[q].w * scale);
        o[q * 64 + l] = u;
    }
}

// ---------- kernel 2: 128^2 3-deep pipeline bf16 MFMA cos-sim + fused argmax ----------
// (byte-identical to R11 — measured 104 µs, MfmaUtil 28.6, bank conflicts 0)
// 4 waves (2M x 2N), per-wave 64x64, acc[4][4]; 3 x 16KB LDS buffers -> 48KB.
// Per tile: vmcnt(4) -> barrier -> STAGE(c+2) -> compute(c). Single barrier/tile
// race-free: barrier at tile c proves all waves done reading buf (c-1)%3
// (== stage target (c+2)%3); per-wave vmcnt proves tile-c data landed.
// Read swizzle: 16B slot ^= ((row>>1)&3)<<4; staging pre-applies the inverse.
#define FENCE_BARRIER() do { asm volatile("" ::: "memory"); \
    __builtin_amdgcn_s_barrier(); asm volatile("" ::: "memory"); } while (0)
#define WAIT_VM4() asm volatile("s_waitcnt vmcnt(4)" ::: "memory")
#define WAIT_VM0() asm volatile("s_waitcnt vmcnt(0)" ::: "memory")

#define STAGEALL(DB) do { \
    gload_lds16(spA0, ldsb + (DB) + (wv * 2 + 0) * 1024); \
    gload_lds16(spA1, ldsb + (DB) + (wv * 2 + 1) * 1024); \
    gload_lds16(spB0, ldsb + (DB) + 8192 + (wv * 2 + 0) * 1024); \
    gload_lds16(spB1, ldsb + (DB) + 8192 + (wv * 2 + 1) * 1024); \
    spA0 += 64; spA1 += 64; spB0 += 64; spB1 += 64; } while (0)

#define COMPUTE(CB) do { \
    bf16x8 af[4], bfr[4]; \
    _Pragma("unroll") for (int mi = 0; mi < 4; ++mi) \
        af[mi] = *(const bf16x8*)(ldsb + (CB) + wM * 4096 + mi * 1024 + rowks); \
    _Pragma("unroll") for (int ni = 0; ni < 4; ++ni) \
        bfr[ni] = *(const bf16x8*)(ldsb + (CB) + 8192 + wN * 4096 + ni * 1024 + rowks); \
    _Pragma("unroll") for (int mi = 0; mi < 4; ++mi) \
    _Pragma("unroll") for (int ni = 0; ni < 4; ++ni) \
        acc[mi][ni] = __builtin_amdgcn_mfma_f32_16x16x32_bf16(af[mi], bfr[ni], acc[mi][ni], 0, 0, 0); \
    } while (0)

#define KT(CB, SB) do { \
    WAIT_VM4(); FENCE_BARRIER(); STAGEALL(SB); COMPUTE(CB); } while (0)

__global__ __launch_bounds__(256, 3) void argmax_gemm(const unsigned short* __restrict__ xnb,
                                                      unsigned long long* __restrict__ partial) {
    __shared__ char ldsb[49152];   // 3 x 16KB buffers

    // T1: XCD-bijective swizzle (2080 = 8*260), then triangular decode
    int wg = (int)blockIdx.x;
    int tile = (wg & 7) * (NWG / 8) + (wg >> 3);
    int by = 0, tr = tile;
    while (tr >= NTIL - by) { tr -= NTIL - by; ++by; }
    const int bx = by + tr;  // bx >= by

    const int rowBase = by * 128, colBase = bx * 128;
    const int tid = (int)threadIdx.x;
    const int wv = tid >> 6;   // 0..3
    const int l = tid & 63;
    const int wM = wv >> 1;    // 2 wave-rows x 64
    const int wN = wv & 1;     // 2 wave-cols x 64

    // read-side: lane l reads row (l&15), 16B slot (l>>4); slot ^= ((row>>1)&3)
    const int rowks = (l & 15) * 64 + (((l >> 4) * 16) ^ (((l >> 1) & 3) << 4));

    // stage-side: source slot = (l&3) ^ ((l>>3)&3)  (inverse of read swizzle)
    const int scol = (((l & 3) ^ ((l >> 3) & 3)) << 4);
    const char* xb = (const char*)xnb;
    const int r0 = (wv * 2 + 0) * 16 + (l >> 2);
    const int r1 = (wv * 2 + 1) * 16 + (l >> 2);
    const char* spA0 = xb + (size_t)(rowBase + r0) * 2048 + scol;
    const char* spA1 = xb + (size_t)(rowBase + r1) * 2048 + scol;
    const char* spB0 = xb + (size_t)(colBase + r0) * 2048 + scol;
    const char* spB1 = xb + (size_t)(colBase + r1) * 2048 + scol;

    f32x4 acc[4][4];
#pragma unroll
    for (int m = 0; m < 4; ++m)
#pragma unroll
        for (int n = 0; n < 4; ++n) acc[m][n] = f32x4{0.f, 0.f, 0.f, 0.f};

    // prologue: stage tiles 0,1 into buf0,buf1 (8 loads in flight)
    STAGEALL(0);
    STAGEALL(16384);

    // main: tiles 0..29; tile c: compute buf c%3, stage tile c+2 -> buf (c+2)%3
    for (int g = 0; g < 10; ++g) {
        KT(0, 32768);
        KT(16384, 0);
        KT(32768, 16384);
    }
    // tail: tile 30 (buf0, vm4), tile 31 (buf1, vm0)
    WAIT_VM4(); FENCE_BARRIER(); COMPUTE(0);
    WAIT_VM0(); FENCE_BARRIER(); COMPUTE(16384);

    // ---- epilogue: fused argmax. C/D: col = lane&15, row = (lane>>4)*4 + reg ----
    // row path: rows of by-block; slot = (bx-by)*2 + wN  in [0, (64-by)*2)
#pragma unroll
    for (int mi = 0; mi < 4; ++mi) {
#pragma unroll
        for (int r = 0; r < 4; ++r) {
            int gi = rowBase + wM * 64 + mi * 16 + (l >> 4) * 4 + r;
            float mx = -3.0f;
            int mc = 0x7FFFFFFF;
#pragma unroll
            for (int ni = 0; ni < 4; ++ni) {
                int gj = colBase + wN * 64 + ni * 16 + (l & 15);
                float v = (gi == gj) ? -2.0f : acc[mi][ni][r];
                if (v > mx) { mx = v; mc = gj; }
            }
#pragma unroll
            for (int off = 1; off < 16; off <<= 1) {
                float omx = __shfl_xor(mx, off, 64);
                int omc = __shfl_xor(mc, off, 64);
                if (omx > mx || (omx == mx && omc < mc)) { mx = omx; mc = omc; }
            }
            if ((l & 15) == 0)
                partial[(size_t)gi * SLOTS + (bx - by) * 2 + wN] = packmax(mx, mc);
        }
    }
    // col path (transpose view, bx > by): slot = (64-bx)*2 + by*2 + wM
    if (bx > by) {
#pragma unroll
        for (int ni = 0; ni < 4; ++ni) {
            int gj = colBase + wN * 64 + ni * 16 + (l & 15);
            float mx = -3.0f;
            int mc = 0x7FFFFFFF;
#pragma unroll
            for (int mi = 0; mi < 4; ++mi) {
#pragma unroll
                for (int r = 0; r < 4; ++r) {
                    int gi = rowBase + wM * 64 + mi * 16 + (l >> 4) * 4 + r;
                    float v = (gi == gj) ? -2.0f : acc[mi][ni][r];
                    if (v > mx) { mx = v; mc = gi; }   // ascending gi, strict >
                }
            }
#pragma unroll
            for (int off = 16; off < 64; off <<= 1) {
                float omx = __shfl_xor(mx, off, 64);
                int omc = __shfl_xor(mc, off, 64);
                if (omx > mx || (omx == mx && omc < mc)) { mx = omx; mc = omc; }
            }
            if ((l >> 4) == 0)
                partial[(size_t)gj * SLOTS + (NTIL - bx) * 2 + by * 2 + wM] = packmax(mx, mc);
        }
    }
}

// ---------- kernel 3: slot-reduce -> (c, j); closed-form distance; atomic mean ----------
// dist^2 = ||xn_i||^2 + ||xn_j||^2 - 2c + 2e-8*(S_i - S_j) + 1024e-16
// (algebraic expansion of sum((xn_i - xn_j + 1e-8)^2); c is the fp32-precision
//  bf16-GEMM cos stored losslessly in the packed slot — same value argmax used.)
__global__ __launch_bounds__(256) void finalize_k(const unsigned long long* __restrict__ partial,
                                                  const float2* __restrict__ sn,
                                                  float* __restrict__ out) {
    int i = blockIdx.x * 4 + (threadIdx.x >> 6);
    int l = threadIdx.x & 63;
    // all 128 slots written for every row (exact partition)
    unsigned long long p = partial[(size_t)i * SLOTS + l];
    {
        unsigned long long o = partial[(size_t)i * SLOTS + 64 + l];
        if (o > p) p = o;
    }
#pragma unroll
    for (int off = 1; off < 64; off <<= 1) {
        unsigned long long o = __shfl_xor(p, off, 64);
        if (o > p) p = o;
    }
    __shared__ float red[4];
    if (l == 0) {
        float c = fmono_inv((unsigned int)(p >> 32));
        int j = (int)(~(unsigned int)(p & 0xFFFFFFFFull));
        float2 si = sn[i];
        float2 sj = sn[j];
        float d2 = si.y + sj.y - 2.0f * c + 2e-8f * (si.x - sj.x) + 1.024e-13f;
        red[threadIdx.x >> 6] = logf(sqrtf(d2) + KEPS);
    }
    __syncthreads();
    if (threadIdx.x == 0) {
        float s = red[0] + red[1] + red[2] + red[3];
        atomicAdd(out, -s * (1.0f / (float)NB));
    }
}

// ---------- launch ----------
extern "C" void kernel_launch(void* const* d_in, const int* in_sizes, int n_in,
                              void* d_out, int out_size, void* d_ws, size_t ws_size,
                              hipStream_t stream) {
    const float* x = (const float*)d_in[0];
    float* out = (float*)d_out;

    char* ws = (char*)d_ws;
    unsigned short* xnb = (unsigned short*)ws;                        // 16 MB
    unsigned long long* partial =
        (unsigned long long*)(ws + (size_t)NB * ND * 2);              // 8 MB
    float2* sn = (float2*)(ws + (size_t)NB * ND * 2 + (size_t)NB * SLOTS * 8);  // 64 KB

    normalize_k<<<NB / 4, 256, 0, stream>>>(x, xnb, sn, out);
    argmax_gemm<<<NWG, 256, 0, stream>>>(xnb, partial);
    finalize_k<<<NB / 4, 256, 0, stream>>>(partial, sn, out);
}